// Round 1
// baseline (1633.170 us; speedup 1.0000x reference)
//
#include <hip/hip_runtime.h>

// FeatureClusteringMinibatch on MI355X (gfx950)
// Pipeline: prep_v -> fused(normalize+GEMM1(split-bf16 MFMA)+softmax+transposed stores)
//           -> split-K GEMM2 (bf16 MFMA, atomic reduce) -> finalize.
// ws layout (requires ~386 MB):
//   [0,512K)      Vn   f32 [256][512]
//   [512K,768K)   Vh   bf16[256][512]
//   [768K,1M)     Vl   bf16[256][512]
//   [1M,1.5M)     S    f32 [256][512]   (atomic target, memset 0)
//   [1.5M,+1K)    csum f32 [256]        (memset 0)
//   [2M, +128M)   CoeffT bf16 [256][N]
//   [2M+128M,+256M) UT bf16 [512][N]

typedef __attribute__((ext_vector_type(8))) short short8;
typedef __attribute__((ext_vector_type(4))) short short4v;
typedef __attribute__((ext_vector_type(4))) float f32x4;

#define KC 256
#define C_DIM 512

static __device__ __forceinline__ short f2bf(float x) {
  union { float f; unsigned u; } v; v.f = x;
  unsigned r = v.u + 0x7fffu + ((v.u >> 16) & 1u);   // RNE to bf16
  return (short)(r >> 16);
}
static __device__ __forceinline__ float bf2f(short s) {
  union { unsigned u; float f; } v; v.u = ((unsigned)(unsigned short)s) << 16;
  return v.f;
}

// ---------------- K1: normalize codebook rows ----------------
__global__ void k_prep_v(const float* __restrict__ V, float* __restrict__ Vn,
                         short* __restrict__ Vh, short* __restrict__ Vl) {
  const int cat = blockIdx.x, t = threadIdx.x;  // 64 threads = 1 wave
  const float* vr = V + (size_t)cat * C_DIM;
  float4 a = ((const float4*)vr)[t * 2];
  float4 b = ((const float4*)vr)[t * 2 + 1];
  float ss = a.x*a.x + a.y*a.y + a.z*a.z + a.w*a.w
           + b.x*b.x + b.y*b.y + b.z*b.z + b.w*b.w;
#pragma unroll
  for (int o = 1; o < 64; o <<= 1) ss += __shfl_xor(ss, o);
  const float sc = 1.f / fmaxf(sqrtf(ss), 1e-12f);
  float u[8] = {a.x*sc, a.y*sc, a.z*sc, a.w*sc, b.x*sc, b.y*sc, b.z*sc, b.w*sc};
  float4* vo = (float4*)(Vn + (size_t)cat * C_DIM) + t * 2;
  vo[0] = make_float4(u[0], u[1], u[2], u[3]);
  vo[1] = make_float4(u[4], u[5], u[6], u[7]);
  short8 h, l;
#pragma unroll
  for (int j = 0; j < 8; ++j) {
    short hh = f2bf(u[j]);
    h[j] = hh;
    l[j] = f2bf(u[j] - bf2f(hh));
  }
  *(short8*)(Vh + (size_t)cat * C_DIM + t * 8) = h;
  *(short8*)(Vl + (size_t)cat * C_DIM + t * 8) = l;
}

// ---------------- K2: fused normalize + GEMM1 + softmax + transposed stores ----
// 64 rows/block, 512 threads (8 waves: wr=wid>>1 row-tile of 16, wc=wid&1 cat-half of 128)
// LDS 160KiB: uh[64][64ch][8] (64K) | ul (64K) | vstage[2][4][256][8] (32K, reused as scratch)
__global__ __launch_bounds__(512, 2) void k_main(
    const float* __restrict__ x, const short* __restrict__ Vh,
    const short* __restrict__ Vl, float* __restrict__ uv,
    short* __restrict__ CoeffT, short* __restrict__ UT, int n_tot) {
  extern __shared__ char smem[];
  const int t = threadIdx.x;
  const int rowbase = blockIdx.x * 64;

  // ---- phase 1: load + normalize + split-bf16 to LDS (XOR-swizzled chunks) ----
  {
    const int row = t >> 3, l8 = t & 7;
    const float* xr = x + (size_t)(rowbase + row) * C_DIM;
    float4 va[8], vb[8];
    float ss = 0.f;
#pragma unroll
    for (int i = 0; i < 8; ++i) {
      const float4* p = (const float4*)(xr + (l8 + 8 * i) * 8);
      va[i] = p[0];
      vb[i] = p[1];
      ss += va[i].x*va[i].x + va[i].y*va[i].y + va[i].z*va[i].z + va[i].w*va[i].w;
      ss += vb[i].x*vb[i].x + vb[i].y*vb[i].y + vb[i].z*vb[i].z + vb[i].w*vb[i].w;
    }
    ss += __shfl_xor(ss, 1); ss += __shfl_xor(ss, 2); ss += __shfl_xor(ss, 4);
    const float sc = 1.f / fmaxf(sqrtf(ss), 1e-12f);
#pragma unroll
    for (int i = 0; i < 8; ++i) {
      const int chunk = l8 + 8 * i;
      const int off = row * 1024 + ((chunk ^ (row & 7)) * 16);
      float uu[8] = {va[i].x*sc, va[i].y*sc, va[i].z*sc, va[i].w*sc,
                     vb[i].x*sc, vb[i].y*sc, vb[i].z*sc, vb[i].w*sc};
      short8 h, l;
#pragma unroll
      for (int j = 0; j < 8; ++j) {
        short hh = f2bf(uu[j]);
        h[j] = hh;
        l[j] = f2bf(uu[j] - bf2f(hh));
      }
      *(short8*)(smem + off) = h;
      *(short8*)(smem + 65536 + off) = l;
    }
  }
  __syncthreads();

  // ---- phase 2: GEMM1, split-bf16 (3 MFMA per product) ----
  const int lane = t & 63, wid = t >> 6;
  const int wr = wid >> 1, wc = wid & 1;
  f32x4 acc[8];
#pragma unroll
  for (int ct = 0; ct < 8; ++ct) acc[ct] = (f32x4){0.f, 0.f, 0.f, 0.f};
  const int stage_cat = t & 255, stage_c4b = t >> 8;

  for (int kk = 0; kk < 16; ++kk) {
    // stage V k-slice into LDS: [plane][c4][cat][8]
#pragma unroll
    for (int p = 0; p < 2; ++p) {
      const short* Vsrc = p ? Vl : Vh;
#pragma unroll
      for (int j = 0; j < 2; ++j) {
        const int c4 = stage_c4b + 2 * j;
        *(uint4*)(smem + 131072 + p * 16384 + c4 * 4096 + stage_cat * 16) =
            *(const uint4*)(Vsrc + (size_t)stage_cat * C_DIM + kk * 32 + c4 * 8);
      }
    }
    __syncthreads();
    const int arow = wr * 16 + (lane & 15);
    const int aoff = arow * 1024 + (((kk * 4 + (lane >> 4)) ^ (arow & 7)) * 16);
    short8 ah = *(const short8*)(smem + aoff);
    short8 al = *(const short8*)(smem + 65536 + aoff);
#pragma unroll
    for (int ct = 0; ct < 8; ++ct) {
      const int cat = wc * 128 + ct * 16 + (lane & 15);
      const int vb0 = 131072 + (lane >> 4) * 4096 + cat * 16;
      short8 bh = *(const short8*)(smem + vb0);
      short8 bl = *(const short8*)(smem + 16384 + vb0);
      acc[ct] = __builtin_amdgcn_mfma_f32_16x16x32_bf16(ah, bh, acc[ct], 0, 0, 0);
      acc[ct] = __builtin_amdgcn_mfma_f32_16x16x32_bf16(ah, bl, acc[ct], 0, 0, 0);
      acc[ct] = __builtin_amdgcn_mfma_f32_16x16x32_bf16(al, bh, acc[ct], 0, 0, 0);
    }
    __syncthreads();
  }

  // ---- UV store (raw cosine sims), D-frag: col=lane&15, row=(lane>>4)*4+i ----
  {
    float* uvb = uv + (size_t)rowbase * KC;
#pragma unroll
    for (int ct = 0; ct < 8; ++ct) {
      const int cat = wc * 128 + ct * 16 + (lane & 15);
#pragma unroll
      for (int i = 0; i < 4; ++i) {
        const int row = wr * 16 + (lane >> 4) * 4 + i;
        uvb[(size_t)row * KC + cat] = acc[ct][i];
      }
    }
  }

  // ---- softmax over 256 cats per row (vstage region reused as scratch) ----
  float* red = (float*)(smem + 131072);  // [2][64]
  float* red2 = red + 128;               // [2][64]
  const int rbase = wr * 16 + (lane >> 4) * 4;
  float mx[4];
#pragma unroll
  for (int i = 0; i < 4; ++i) {
    float m = acc[0][i];
#pragma unroll
    for (int ct = 1; ct < 8; ++ct) m = fmaxf(m, acc[ct][i]);
    m = fmaxf(m, __shfl_xor(m, 1));
    m = fmaxf(m, __shfl_xor(m, 2));
    m = fmaxf(m, __shfl_xor(m, 4));
    m = fmaxf(m, __shfl_xor(m, 8));
    mx[i] = m;
  }
  if ((lane & 15) == 0) {
#pragma unroll
    for (int i = 0; i < 4; ++i) red[wc * 64 + rbase + i] = mx[i];
  }
  __syncthreads();
#pragma unroll
  for (int i = 0; i < 4; ++i) mx[i] = fmaxf(red[rbase + i], red[64 + rbase + i]);
  float pr[8][4];
  float sm[4] = {0.f, 0.f, 0.f, 0.f};
#pragma unroll
  for (int ct = 0; ct < 8; ++ct)
#pragma unroll
    for (int i = 0; i < 4; ++i) {
      pr[ct][i] = expf(acc[ct][i] - mx[i]);
      sm[i] += pr[ct][i];
    }
#pragma unroll
  for (int i = 0; i < 4; ++i) {
    sm[i] += __shfl_xor(sm[i], 1);
    sm[i] += __shfl_xor(sm[i], 2);
    sm[i] += __shfl_xor(sm[i], 4);
    sm[i] += __shfl_xor(sm[i], 8);
  }
  if ((lane & 15) == 0) {
#pragma unroll
    for (int i = 0; i < 4; ++i) red2[wc * 64 + rbase + i] = sm[i];
  }
  __syncthreads();
  float rinv[4];
#pragma unroll
  for (int i = 0; i < 4; ++i) rinv[i] = 1.f / (red2[rbase + i] + red2[64 + rbase + i]);

  // ---- CoeffT store: [cat][n], 4 consecutive rows per lane -> 8B stores ----
#pragma unroll
  for (int ct = 0; ct < 8; ++ct) {
    const int cat = wc * 128 + ct * 16 + (lane & 15);
    short4v cv;
#pragma unroll
    for (int i = 0; i < 4; ++i) cv[i] = f2bf(pr[ct][i] * rinv[i]);
    *(short4v*)(CoeffT + (size_t)cat * n_tot + rowbase + rbase) = cv;
  }

  // ---- UT gather: transpose uh (bf16 high plane) from LDS to [c][n] global ----
  {
    const int c = t;  // 0..511
    short* utp = UT + (size_t)c * n_tot + rowbase;
#pragma unroll
    for (int j = 0; j < 8; ++j) {
      short8 v;
#pragma unroll
      for (int e = 0; e < 8; ++e) {
        const int r = j * 8 + e;
        v[e] = *(const short*)(smem + r * 1024 + (((c >> 3) ^ (r & 7)) * 16) + (c & 7) * 2);
      }
      *(short8*)(utp + j * 8) = v;
    }
  }
}

// ---------------- K3: GEMM2  S[k][c] = sum_n CoeffT[k][n]*UT[c][n], + csum ----
// grid 256 = 128 n-chunks x 2 c-halves; 512 thr (8 waves: wr kcat-tile 64, wc c-tile 128)
__global__ __launch_bounds__(512, 2) void k_gemm2(
    const short* __restrict__ CoeffT, const short* __restrict__ UT,
    float* __restrict__ S, float* __restrict__ csum, int n_tot) {
  const int t = threadIdx.x, lane = t & 63, wid = t >> 6;
  const int wr = wid >> 1, wc = wid & 1;
  const int chalf = blockIdx.x & 1, nb = blockIdx.x >> 1;
  const int nchunk = n_tot >> 7;  // 2048
  const size_t nbase = (size_t)nb * nchunk;
  f32x4 acc[4][8];
#pragma unroll
  for (int at = 0; at < 4; ++at)
#pragma unroll
    for (int bt = 0; bt < 8; ++bt) acc[at][bt] = (f32x4){0.f, 0.f, 0.f, 0.f};
  float kcs[4] = {0.f, 0.f, 0.f, 0.f};
  const int nsteps = nchunk >> 5;  // 64
  for (int ns = 0; ns < nsteps; ++ns) {
    const size_t n0 = nbase + ns * 32 + (lane >> 4) * 8;
    short8 a[4], b[8];
#pragma unroll
    for (int at = 0; at < 4; ++at)
      a[at] = *(const short8*)(CoeffT + (size_t)(wr * 64 + at * 16 + (lane & 15)) * n_tot + n0);
#pragma unroll
    for (int bt = 0; bt < 8; ++bt)
      b[bt] = *(const short8*)(UT + (size_t)(chalf * 256 + wc * 128 + bt * 16 + (lane & 15)) * n_tot + n0);
#pragma unroll
    for (int at = 0; at < 4; ++at)
#pragma unroll
      for (int bt = 0; bt < 8; ++bt)
        acc[at][bt] = __builtin_amdgcn_mfma_f32_16x16x32_bf16(a[at], b[bt], acc[at][bt], 0, 0, 0);
    if (wc == 0 && chalf == 0) {
#pragma unroll
      for (int at = 0; at < 4; ++at) {
        float s8 = 0.f;
#pragma unroll
        for (int e = 0; e < 8; ++e) s8 += bf2f(a[at][e]);
        kcs[at] += s8;
      }
    }
  }
#pragma unroll
  for (int at = 0; at < 4; ++at)
#pragma unroll
    for (int bt = 0; bt < 8; ++bt)
#pragma unroll
      for (int i = 0; i < 4; ++i) {
        const int kc = wr * 64 + at * 16 + (lane >> 4) * 4 + i;
        const int cc = chalf * 256 + wc * 128 + bt * 16 + (lane & 15);
        atomicAdd(&S[kc * C_DIM + cc], acc[at][bt][i]);
      }
  if (wc == 0 && chalf == 0) {
#pragma unroll
    for (int at = 0; at < 4; ++at) {
      kcs[at] += __shfl_xor(kcs[at], 16);
      kcs[at] += __shfl_xor(kcs[at], 32);
    }
    if (lane < 16) {
#pragma unroll
      for (int at = 0; at < 4; ++at) atomicAdd(&csum[wr * 64 + at * 16 + lane], kcs[at]);
    }
  }
}

// ---------------- K4: finalize V_new = (Vc*Vn + S)/(Vc+csum), V_count ----
__global__ void k_final(const float* __restrict__ Vn, const float* __restrict__ S,
                        const float* __restrict__ csum, const float* __restrict__ Vcnt,
                        float* __restrict__ vnew, float* __restrict__ vcnt_out) {
  const int g = blockIdx.x * 256 + threadIdx.x;  // 0..32767 (float4 granules)
  const int k = g >> 7;                          // 128 float4 per row
  const float cs = csum[k], vc = Vcnt[k];
  const float inv = 1.f / (vc + cs);
  float4 vn = ((const float4*)Vn)[g];
  float4 s = ((const float4*)S)[g];
  float4 o = make_float4((vc * vn.x + s.x) * inv, (vc * vn.y + s.y) * inv,
                         (vc * vn.z + s.z) * inv, (vc * vn.w + s.w) * inv);
  ((float4*)vnew)[g] = o;
  if (g < KC) vcnt_out[g] = vc + csum[g];
}

extern "C" void kernel_launch(void* const* d_in, const int* in_sizes, int n_in,
                              void* d_out, int out_size, void* d_ws, size_t ws_size,
                              hipStream_t stream) {
  const float* x = (const float*)d_in[0];
  const float* Vbuf = (const float*)d_in[1];
  const float* Vcnt = (const float*)d_in[2];
  const int n_tot = in_sizes[0] / C_DIM;  // 262144
  float* out = (float*)d_out;
  float* uv = out;                               // [N][256]
  float* vnew = out + (size_t)n_tot * KC;        // [256][512]
  float* vcnt_out = vnew + (size_t)KC * C_DIM;   // [256]
  char* ws = (char*)d_ws;
  float* Vn = (float*)(ws);
  short* Vh = (short*)(ws + 524288);
  short* Vl = (short*)(ws + 786432);
  float* S = (float*)(ws + 1048576);
  float* csum = (float*)(ws + 1572864);
  short* CoeffT = (short*)(ws + 2097152);
  short* UT = (short*)(ws + 2097152 + (size_t)KC * n_tot * 2);

  hipMemsetAsync(ws + 1048576, 0, 524288 + 1024, stream);  // zero S + csum
  k_prep_v<<<KC, 64, 0, stream>>>(Vbuf, Vn, Vh, Vl);
  hipFuncSetAttribute((const void*)k_main,
                      hipFuncAttributeMaxDynamicSharedMemorySize, 163840);
  k_main<<<n_tot / 64, 512, 163840, stream>>>(x, Vh, Vl, uv, CoeffT, UT, n_tot);
  k_gemm2<<<256, 512, 0, stream>>>(CoeffT, UT, S, csum, n_tot);
  k_final<<<128, 256, 0, stream>>>(Vn, S, csum, Vcnt, vnew, vcnt_out);
}